// Round 12
// baseline (53.841 us; speedup 1.0000x reference)
//
#include <hip/hip_runtime.h>
#include <hip/hip_bf16.h>

#define BB 64
#define NN 96
#define FF 16
#define HH 128
#define KK 64
#define LL 3
#define CUTOFF_F 10.0f
#define GAMMA_F 10.0f

#define W3_BLOCKS 99
#define WA2_CP 12
#define WO1_CP 4
#define CNT_BLOCKS BB

// ---------------------------------------------------------------------------
// pre_kernel:
//   [0,99):    W3 rows computed as before but stored K-QUAD-INTERLEAVED:
//              W3i[l][(kk>>2)*128+h][kk&3]; bias row -> c3.
//   [99,111):  Wa2i = k-quad-interleaved copy of Wa2 (per 16KB chunk)
//   [111,115): Wo1i = same for Wo1
//   [115,179): cnt[b] = #valid atoms; zero out[b]
// ---------------------------------------------------------------------------
__global__ __launch_bounds__(256) void pre_kernel(
    const float* __restrict__ Wrbf, const float* __restrict__ brbf,
    const float* __restrict__ Wpair, const float* __restrict__ bpair,
    const float* __restrict__ Wa1, const float* __restrict__ Wa2,
    const float* __restrict__ Wo1,
    const int* __restrict__ batch,
    float* __restrict__ W3i, float* __restrict__ c3,
    float* __restrict__ Wa2i, float* __restrict__ Wo1i,
    float* __restrict__ cnt, float* __restrict__ out)
{
    const int bid = blockIdx.x;
    const int tid = threadIdx.x;
    if (bid < W3_BLOCKS) {
        __shared__ float sW2[2][HH];
        const int l    = bid / 33;
        const int r0   = (bid % 33) * 2;
        const int half = tid >> 7;
        const int h    = tid & 127;
        const int kk   = r0 + half;       // 0..65 (65 inactive)
        const bool active = (kk <= KK);
        if (active) {
            const float* Wp = Wpair + l * HH * HH + h;
            const float* arow;
            float acc;
            if (kk < KK) { arow = Wrbf + (l * KK + kk) * HH; acc = 0.f; }
            else         { arow = brbf + l * HH;             acc = bpair[l * HH + h]; }
            #pragma unroll 8
            for (int m = 0; m < HH; ++m) acc += arow[m] * Wp[m * HH];
            sW2[half][h] = acc;
        }
        __syncthreads();
        if (active) {
            const float* Wa = Wa1 + l * HH * HH + h;
            const float* row = sW2[half];
            float a3 = 0.f;
            #pragma unroll 8
            for (int m = 0; m < HH; ++m) a3 += row[m] * Wa[m * HH];
            if (kk < KK)
                W3i[l * KK * HH + (((kk >> 2) * HH + h) << 2) + (kk & 3)] = a3;
            else
                c3[l * HH + h] = a3;
        }
    } else if (bid < W3_BLOCKS + WA2_CP + WO1_CP) {
        // interleave-copy one 16KB chunk (32 k-rows x 128)
        int ci = bid - W3_BLOCKS;
        const float* src;
        float* dst;
        if (ci < WA2_CP) { src = Wa2 + ci * 4096; dst = Wa2i + ci * 4096; }
        else             { src = Wo1 + (ci - WA2_CP) * 4096; dst = Wo1i + (ci - WA2_CP) * 4096; }
        for (int e = tid; e < 4096; e += 256) {
            int k = e >> 7, h = e & 127;
            dst[(((k >> 2) * HH + h) << 2) + (k & 3)] = src[e];
        }
    } else {
        int b = bid - (W3_BLOCKS + WA2_CP + WO1_CP);
        __shared__ int c[4];
        bool v = (tid < NN) && (batch[b * NN + tid] != -1);
        unsigned long long m = __ballot(v);
        if ((tid & 63) == 0) c[tid >> 6] = __popcll(m);
        __syncthreads();
        if (tid == 0) {
            cnt[b] = (float)(c[0] + c[1] + c[2] + c[3]);
            out[b] = 0.f;                 // zero the atomic target each call
        }
    }
}

// ---------------------------------------------------------------------------
// chain_kernel: R11 skeleton (AT=8, 256thr, 768 blocks = 3/CU, 2x16KB DMA
// ping-pong, vmcnt(0)+syncthreads consume) with k-quad weight layout:
// per 4-k group: 1 ds_read_b128 weight (4 k's, conflict-free) + 4 broadcast
// b128 operands (atom-major [at][k]) -> 16 FMA. LDS instrs/phase: 64 -> 40.
// ---------------------------------------------------------------------------
#define AT 8
#define CHF 4096              // floats per 16KB chunk (32 k x 128 ch)
#define SSTW 68               // sST row stride (64 k + pad)
#define TBW 132               // tbT/hbT row stride (128 k + pad)
#define CW 12                 // sX row stride

typedef const __attribute__((address_space(1))) void* gp1_t;
typedef __attribute__((address_space(3))) void* lp3_t;

__device__ __forceinline__ void stage16k(const float* g, float* l, int tid)
{
    const int lane = tid & 63, wv = tid >> 6;
    #pragma unroll
    for (int j = 0; j < 4; ++j) {
        const int base = j * 256 + wv * 64;            // float4 units
        __builtin_amdgcn_global_load_lds((gp1_t)(g + (size_t)(base + lane) * 4),
                                         (lp3_t)(l + (size_t)base * 4), 16, 0, 0);
    }
}

#define VMCNT0() asm volatile("s_waitcnt vmcnt(0)" ::: "memory")

__device__ __forceinline__ float silu1(float v) { return v / (1.f + __expf(-v)); }

// one 16KB chunk (32 k) of a GEMM: 8 quad-groups; SRC rows at0..at0+3, k-base KB
#define GEMMQ(ACC, WBP, SRC, KB) do {                                       \
    _Pragma("unroll")                                                       \
    for (int g5 = 0; g5 < 8; ++g5) {                                        \
        float4 w4 = *(const float4*)&(WBP)[((g5 * HH + hh) << 2)];          \
        float4 u0 = *(const float4*)&SRC[at0 + 0][(KB) + g5 * 4];           \
        float4 u1 = *(const float4*)&SRC[at0 + 1][(KB) + g5 * 4];           \
        float4 u2 = *(const float4*)&SRC[at0 + 2][(KB) + g5 * 4];           \
        float4 u3 = *(const float4*)&SRC[at0 + 3][(KB) + g5 * 4];           \
        ACC[0] += w4.x*u0.x + w4.y*u0.y + w4.z*u0.z + w4.w*u0.w;            \
        ACC[1] += w4.x*u1.x + w4.y*u1.y + w4.z*u1.z + w4.w*u1.w;            \
        ACC[2] += w4.x*u2.x + w4.y*u2.y + w4.z*u2.z + w4.w*u2.w;            \
        ACC[3] += w4.x*u3.x + w4.y*u3.y + w4.z*u3.z + w4.w*u3.w;            \
    }                                                                       \
} while (0)

#define PHASE_END(STAGEPTR) do {                                            \
    VMCNT0(); __syncthreads();                                              \
    stage16k((STAGEPTR), wb[_slot], tid); _slot ^= 1;                       \
} while (0)
#define PHASE_END_NOSTAGE() do { VMCNT0(); __syncthreads(); _slot ^= 1; } while (0)

__global__ __launch_bounds__(256, 3) void chain_kernel(
    const float* __restrict__ X, const float* __restrict__ R,
    const float* __restrict__ We, const float* __restrict__ be,
    const float* __restrict__ ba1, const float* __restrict__ ba2,
    const float* __restrict__ bo1, const float* __restrict__ Wo2,
    const float* __restrict__ bo2, const float* __restrict__ W3i,
    const float* __restrict__ Wa2i, const float* __restrict__ Wo1i,
    const float* __restrict__ c3, const float* __restrict__ cnt,
    float* __restrict__ out)
{
    __shared__ __align__(16) float wb[2][CHF];     // 32KB weight ping-pong
    __shared__ __align__(16) float sST[AT][SSTW];  // S, atom-major (persists)
    __shared__ __align__(16) float tbT[AT][TBW];   // t, atom-major (sD/sRf alias)
    __shared__ __align__(16) float hbT[AT][TBW];   // h for head
    __shared__ __align__(16) float sX[FF][CW];
    __shared__ float po[4][4];

    const int tid  = threadIdx.x;
    const int hh   = tid & 127;          // channel
    const int half = tid >> 7;           // atom half
    const int wv   = tid >> 6;           // wave 0..3
    const int at0  = half * 4;           // this thread's atoms at0..at0+3
    const int hc   = half * 4;           // sX column base
    const int a0   = blockIdx.x * AT;    // 96 % 8 == 0 -> block within one molecule
    const int b    = a0 / NN;
    const int lbase = a0 - b * NN;       // molecule-local first atom
    const float cb = cnt[b];
    const int nv   = (int)cb;            // valid atoms = molecule-local prefix

    float* sD  = &tbT[0][0];             // 768 floats distances (alias, dead later)
    float* sRf = sD + AT * NN;           // 288 floats molecule R (768+288=1056=8*132)

    // ---- stage molecule R, X^T ----
    for (int t = tid; t < NN * 3; t += 256) sRf[t] = R[b * NN * 3 + t];
    if (tid < AT * FF) {
        int a = tid >> 4, f = tid & 15;
        sX[f][a] = X[(a0 + a) * FF + f];
    }
    __syncthreads();

    // ---- phase 1: distance table D[j][i] ----
    for (int e = tid; e < AT * NN; e += 256) {
        int j = e / NN, i = e - j * NN;
        float dx = sRf[i * 3 + 0] - sRf[(lbase + j) * 3 + 0];
        float dy = sRf[i * 3 + 1] - sRf[(lbase + j) * 3 + 1];
        float dz = sRf[i * 3 + 2] - sRf[(lbase + j) * 3 + 2];
        sD[e] = sqrtf(dx * dx + dy * dy + dz * dz);
    }
    __syncthreads();

    // ---- issue first two weight chunks (hidden under S-phase) ----
    stage16k(W3i, wb[0], tid);
    stage16k(W3i + CHF, wb[1], tid);
    int _slot = 0;

    // ---- phase 2: sST[j][k] = sum_{i<nv} exp(-g*(D[j][i]-ck)^2) ----
    {
        const int k = tid & 63;
        const float ck = (float)k * (CUTOFF_F / (float)(KK - 1));
        #pragma unroll
        for (int r = 0; r < 2; ++r) {
            int j = 2 * wv + r;              // wave-uniform
            if (lbase + j >= nv) { sST[j][k] = 0.f; continue; }
            const float* Dr = sD + j * NN;
            float acc = 0.f;
            for (int i = 0; i < nv; ++i) {
                float u = Dr[i] - ck;
                acc += __expf(-GAMMA_F * u * u);
            }
            sST[j][k] = acc;
        }
    }

    // ---- embedding: h = X@We + be ----
    float h[4];
    {
        float acc[4] = {0, 0, 0, 0};
        const float* wp = We + hh;
        #pragma unroll
        for (int f = 0; f < FF; ++f) {
            float w = wp[f * HH];
            float4 x4 = *(const float4*)&sX[f][hc];
            acc[0] += w * x4.x; acc[1] += w * x4.y;
            acc[2] += w * x4.z; acc[3] += w * x4.w;
        }
        float bee = be[hh];
        #pragma unroll
        for (int a = 0; a < 4; ++a) h[a] = acc[a] + bee;
    }

    VMCNT0();
    __syncthreads();   // chunks 0,1 ready; sST visible; sD/sRf dead

    // ---- layers: 6 phases each ----
    for (int l = 0; l < LL; ++l) {
        const float* WaL = Wa2i + (size_t)l * HH * HH;
        // GEMM1: acc = S @ W3[l]
        float acc[4] = {0, 0, 0, 0};
        GEMMQ(acc, wb[0], sST, 0);                   // phase 6l+0
        PHASE_END(WaL);                              // -> Wa2i rows 0-31
        GEMMQ(acc, wb[1], sST, 32);                  // phase 6l+1
        {
            float biasv = cb * c3[l * HH + hh] + ba1[l * HH + hh];
            tbT[at0 + 0][hh] = silu1(acc[0] + biasv);
            tbT[at0 + 1][hh] = silu1(acc[1] + biasv);
            tbT[at0 + 2][hh] = silu1(acc[2] + biasv);
            tbT[at0 + 3][hh] = silu1(acc[3] + biasv);
        }
        PHASE_END(WaL + CHF);                        // -> Wa2i rows 32-63
        // GEMM2: h += t @ Wa2[l]
        float acc2[4] = {0, 0, 0, 0};
        GEMMQ(acc2, wb[0], tbT, 0);                  // phase 6l+2
        PHASE_END(WaL + 2 * CHF);                    // -> Wa2i rows 64-95
        GEMMQ(acc2, wb[1], tbT, 32);                 // phase 6l+3
        PHASE_END(WaL + 3 * CHF);                    // -> Wa2i rows 96-127
        GEMMQ(acc2, wb[0], tbT, 64);                 // phase 6l+4
        PHASE_END((l < LL - 1) ? (W3i + (size_t)(l + 1) * 2 * CHF) : Wo1i);
        GEMMQ(acc2, wb[1], tbT, 96);                 // phase 6l+5
        {
            float ba2v = ba2[l * HH + hh];
            #pragma unroll
            for (int a = 0; a < 4; ++a) h[a] += acc2[a] + ba2v;
            if (l == LL - 1) {                        // stage h for the head
                hbT[at0 + 0][hh] = h[0];
                hbT[at0 + 1][hh] = h[1];
                hbT[at0 + 2][hh] = h[2];
                hbT[at0 + 3][hh] = h[3];
            }
        }
        PHASE_END((l < LL - 1) ? (W3i + (size_t)(l + 1) * 2 * CHF + CHF) : (Wo1i + CHF));
    }

    // ---- output head: phases 18..21 over Wo1i, reading hbT ----
    float acc[4] = {0, 0, 0, 0};
    GEMMQ(acc, wb[0], hbT, 0);                       // phase 18
    PHASE_END(Wo1i + 2 * CHF);
    GEMMQ(acc, wb[1], hbT, 32);                      // phase 19
    PHASE_END(Wo1i + 3 * CHF);
    GEMMQ(acc, wb[0], hbT, 64);                      // phase 20
    PHASE_END_NOSTAGE();
    GEMMQ(acc, wb[1], hbT, 96);                      // phase 21

    float bo1v = bo1[hh], wo2v = Wo2[hh];
    float p4[4];
    #pragma unroll
    for (int a = 0; a < 4; ++a) p4[a] = silu1(acc[a] + bo1v) * wo2v;
    // reduce over the 64 channel lanes of each wave
    #pragma unroll
    for (int a = 0; a < 4; ++a) {
        float r = p4[a];
        r += __shfl_down(r, 32); r += __shfl_down(r, 16);
        r += __shfl_down(r, 8);  r += __shfl_down(r, 4);
        r += __shfl_down(r, 2);  r += __shfl_down(r, 1);
        p4[a] = r;
    }
    if ((tid & 63) == 0) {
        #pragma unroll
        for (int a = 0; a < 4; ++a) po[wv][a] = p4[a];
    }
    __syncthreads();
    if (tid == 0) {
        // atom j (0..7): half g2=j>>2 handled by waves 2*g2 and 2*g2+1
        float bo2v = bo2[0];
        float sum = 0.f;
        #pragma unroll
        for (int j = 0; j < AT; ++j) {
            if (lbase + j < nv) {
                int g2 = j >> 2, a = j & 3;
                sum += po[2 * g2][a] + po[2 * g2 + 1][a] + bo2v;
            }
        }
        atomicAdd(out + b, sum / cb);
    }
}

extern "C" void kernel_launch(void* const* d_in, const int* in_sizes, int n_in,
                              void* d_out, int out_size, void* d_ws, size_t ws_size,
                              hipStream_t stream) {
    const float* X     = (const float*)d_in[0];
    const float* R     = (const float*)d_in[1];
    const int*   batch = (const int*)  d_in[2];
    const float* We    = (const float*)d_in[3];
    const float* be    = (const float*)d_in[4];
    const float* Wrbf  = (const float*)d_in[5];
    const float* brbf  = (const float*)d_in[6];
    const float* Wpair = (const float*)d_in[7];
    const float* bpair = (const float*)d_in[8];
    const float* Wa1   = (const float*)d_in[9];
    const float* ba1   = (const float*)d_in[10];
    const float* Wa2   = (const float*)d_in[11];
    const float* ba2   = (const float*)d_in[12];
    const float* Wo1   = (const float*)d_in[13];
    const float* bo1   = (const float*)d_in[14];
    const float* Wo2   = (const float*)d_in[15];
    const float* bo2   = (const float*)d_in[16];

    float* w    = (float*)d_ws;
    float* W3i  = w;                       // L*K*H  = 24576
    float* c3   = W3i + LL * KK * HH;      // L*H    = 384
    float* Wa2i = c3 + LL * HH;            // L*H*H  = 49152
    float* Wo1i = Wa2i + LL * HH * HH;     // H*H    = 16384
    float* cnt  = Wo1i + HH * HH;          // B      = 64
    float* out  = (float*)d_out;

    hipLaunchKernelGGL(pre_kernel,
                       dim3(W3_BLOCKS + WA2_CP + WO1_CP + CNT_BLOCKS), dim3(256),
                       0, stream, Wrbf, brbf, Wpair, bpair, Wa1, Wa2, Wo1, batch,
                       W3i, c3, Wa2i, Wo1i, cnt, out);
    hipLaunchKernelGGL(chain_kernel, dim3(BB * NN / AT), dim3(256), 0, stream,
                       X, R, We, be, ba1, ba2, bo1, Wo2, bo2,
                       W3i, Wa2i, Wo1i, c3, cnt, out);
}